// Round 6
// baseline (168.301 us; speedup 1.0000x reference)
//
#include <hip/hip_runtime.h>

#define S_LEN 2048
#define BATCH 4
#define DMODEL 512
#define NHEAD 8
#define HDIM 64
#define ROWS (BATCH * S_LEN) /* 8192 */

using short8 = __attribute__((ext_vector_type(8))) short;
using f32x4  = __attribute__((ext_vector_type(4))) float;

__device__ __forceinline__ unsigned short f2bf(float f) {
  unsigned int u = __builtin_bit_cast(unsigned int, f);
  u += 0x7fffu + ((u >> 16) & 1u);
  return (unsigned short)(u >> 16);
}
__device__ __forceinline__ float bf2f(unsigned short h) {
  unsigned int u = ((unsigned int)h) << 16;
  return __builtin_bit_cast(float, u);
}
__device__ __forceinline__ void glds16(const void* g, void* l) {
  __builtin_amdgcn_global_load_lds((const __attribute__((address_space(1))) unsigned*)g,
                                   (__attribute__((address_space(3))) unsigned*)l, 16, 0, 0);
}

// ---------------- prep: fp32->bf16 cvt (blocks 0..2047) + 4 weight transposes ------
__global__ __launch_bounds__(256) void prep_kernel(const float* __restrict__ x,
                                                   const float* __restrict__ Wq,
                                                   const float* __restrict__ Wk,
                                                   const float* __restrict__ Wv,
                                                   const float* __restrict__ Wo,
                                                   unsigned short* __restrict__ xb,
                                                   unsigned short* __restrict__ WqkT,
                                                   unsigned short* __restrict__ WvT,
                                                   unsigned short* __restrict__ WoT) {
  __shared__ float t[32][33];
  const int blk = blockIdx.x, tid = threadIdx.x;
  if (blk < 2048) {
    const int base = (blk * 256 + tid) * 8;
    float4 f0 = *(const float4*)(x + base);
    float4 f1 = *(const float4*)(x + base + 4);
    uint4 o;
    o.x = (unsigned)f2bf(f0.x) | ((unsigned)f2bf(f0.y) << 16);
    o.y = (unsigned)f2bf(f0.z) | ((unsigned)f2bf(f0.w) << 16);
    o.z = (unsigned)f2bf(f1.x) | ((unsigned)f2bf(f1.y) << 16);
    o.w = (unsigned)f2bf(f1.z) | ((unsigned)f2bf(f1.w) << 16);
    *(uint4*)(xb + base) = o;
    return;
  }
  const int tb = blk - 2048;   // 0..1023
  const int which = tb >> 8;   // matrix id
  const int tile = tb & 255;   // 16x16 grid of 32x32 tiles
  const float* W = which == 0 ? Wq : which == 1 ? Wk : which == 2 ? Wv : Wo;
  unsigned short* WT = which == 0 ? WqkT : which == 1 ? (WqkT + 512 * 512)
                      : which == 2 ? WvT : WoT;
  const int tx = tid & 31, ty = tid >> 5; // 32 x 8
  const int x0 = (tile & 15) * 32, y0 = (tile >> 4) * 32;
#pragma unroll
  for (int r = 0; r < 4; r++)
    t[ty + 8 * r][tx] = W[(size_t)(y0 + ty + 8 * r) * DMODEL + x0 + tx];
  __syncthreads();
#pragma unroll
  for (int r = 0; r < 4; r++)
    WT[(size_t)(x0 + ty + 8 * r) * DMODEL + y0 + tx] = f2bf(t[tx][ty + 8 * r]);
}

// ---------------- fused QKV GEMM: 1D grid, 768 blocks -----------------------------
__global__ __launch_bounds__(256, 2) void gemm_qkv_kernel(const unsigned short* __restrict__ xb,
                                                          const unsigned short* __restrict__ WqkT,
                                                          const unsigned short* __restrict__ WvT,
                                                          const float* __restrict__ bq,
                                                          const float* __restrict__ bk,
                                                          const float* __restrict__ bv,
                                                          const int* __restrict__ x_len,
                                                          unsigned short* __restrict__ Qb,
                                                          unsigned short* __restrict__ Kb,
                                                          unsigned short* __restrict__ Vt) {
  constexpr int K = DMODEL;
  __shared__ __align__(16) char smem[16384];
  char* As = smem;
  char* Bs = smem + 8192;
  const int bid = blockIdx.x;
  const bool vmode = bid < 256;
  const unsigned short *A, *Bt;
  int m0, n0;
  if (vmode) {
    m0 = (bid & 3) * 128;   // feature
    n0 = (bid >> 2) * 128;  // row
    A = WvT; Bt = xb;
  } else {
    const int q = bid - 256;
    m0 = (q >> 3) * 128;    // row
    n0 = (q & 7) * 128;     // col (0-511 Q, 512-1023 K)
    A = xb; Bt = WqkT;
    const int xl = x_len[m0 >> 11];
    const int s0 = m0 & 2047;
    if (n0 >= DMODEL) { if (s0 >= xl) return; }        // K rows >= xlen unobserved
    else if (s0 >= xl + 128) return;                   // Q rows >= xlen+128 unobserved
  }
  const int tid = threadIdx.x;
  const int wave = tid >> 6, lane = tid & 63;
  const int wr = wave >> 1, wc = wave & 1;
  const int lm = lane & 15, lq = lane >> 4;
  const int lr = lane >> 2;
  const int lc = (lane & 3) ^ ((lane >> 3) & 3);
  const unsigned short* gA0 = A + (size_t)(m0 + wave * 16 + lr) * K + lc * 8;
  const unsigned short* gA1 = A + (size_t)(m0 + (wave + 4) * 16 + lr) * K + lc * 8;
  const unsigned short* gB0 = Bt + (size_t)(n0 + wave * 16 + lr) * K + lc * 8;
  const unsigned short* gB1 = Bt + (size_t)(n0 + (wave + 4) * 16 + lr) * K + lc * 8;
  char* lA0 = As + wave * 1024 + lane * 16;
  char* lA1 = As + (wave + 4) * 1024 + lane * 16;
  char* lB0 = Bs + wave * 1024 + lane * 16;
  char* lB1 = Bs + (wave + 4) * 1024 + lane * 16;
  const int sw = (lm >> 1) & 3;
  int aoff[4], boff[4];
#pragma unroll
  for (int mi = 0; mi < 4; mi++)
    aoff[mi] = (wr * 64 + mi * 16 + lm) * 64 + (lq ^ sw) * 16;
#pragma unroll
  for (int ni = 0; ni < 4; ni++)
    boff[ni] = (wc * 64 + ni * 16 + lm) * 64 + (lq ^ sw) * 16;

  f32x4 acc[4][4] = {};
  for (int k0 = 0; k0 < K; k0 += 32) {
    __syncthreads();
    glds16(gA0 + k0, lA0);
    glds16(gA1 + k0, lA1);
    glds16(gB0 + k0, lB0);
    glds16(gB1 + k0, lB1);
    __syncthreads();
    short8 af[4], bfr[4];
#pragma unroll
    for (int mi = 0; mi < 4; mi++) af[mi] = *(const short8*)(As + aoff[mi]);
#pragma unroll
    for (int ni = 0; ni < 4; ni++) bfr[ni] = *(const short8*)(Bs + boff[ni]);
#pragma unroll
    for (int mi = 0; mi < 4; mi++)
#pragma unroll
      for (int ni = 0; ni < 4; ni++)
        acc[mi][ni] = __builtin_amdgcn_mfma_f32_16x16x32_bf16(af[mi], bfr[ni], acc[mi][ni], 0, 0, 0);
  }
#pragma unroll
  for (int mi = 0; mi < 4; mi++) {
    const int row0 = m0 + wr * 64 + mi * 16 + lq * 4;
#pragma unroll
    for (int ni = 0; ni < 4; ni++) {
      const int col = n0 + wc * 64 + ni * 16 + lm;
#pragma unroll
      for (int r = 0; r < 4; r++) {
        const int row = row0 + r;
        const float v = acc[mi][ni][r];
        if (vmode) {
          Vt[(size_t)row * ROWS + col] = f2bf(v + bv[row]);
        } else if (col < DMODEL) {
          Qb[(size_t)row * DMODEL + col] = f2bf(v + bq[col]);
        } else {
          Kb[(size_t)row * DMODEL + (col - DMODEL)] = f2bf(v + bk[col - DMODEL]);
        }
      }
    }
  }
}

// ---------------- output projection GEMM (fp32 out, bias by col, tail skip) -------
__global__ __launch_bounds__(256, 2) void gemm_out_kernel(const unsigned short* __restrict__ A,
                                                          const unsigned short* __restrict__ Bt,
                                                          const float* __restrict__ bias,
                                                          const int* __restrict__ x_len,
                                                          float* __restrict__ out) {
  constexpr int K = DMODEL;
  __shared__ __align__(16) char smem[16384];
  char* As = smem;
  char* Bs = smem + 8192;
  const int m0 = blockIdx.y * 128, n0 = blockIdx.x * 128;
  // tail rows (>= xlen+128) are batch-uniform: tail_kernel broadcasts them
  {
    const int xl = x_len[m0 >> 11];
    if ((m0 & 2047) >= min(S_LEN, xl + 128)) return;
  }
  const int tid = threadIdx.x;
  const int wave = tid >> 6, lane = tid & 63;
  const int wr = wave >> 1, wc = wave & 1;
  const int lm = lane & 15, lq = lane >> 4;
  const int lr = lane >> 2;
  const int lc = (lane & 3) ^ ((lane >> 3) & 3);
  const unsigned short* gA0 = A + (size_t)(m0 + wave * 16 + lr) * K + lc * 8;
  const unsigned short* gA1 = A + (size_t)(m0 + (wave + 4) * 16 + lr) * K + lc * 8;
  const unsigned short* gB0 = Bt + (size_t)(n0 + wave * 16 + lr) * K + lc * 8;
  const unsigned short* gB1 = Bt + (size_t)(n0 + (wave + 4) * 16 + lr) * K + lc * 8;
  char* lA0 = As + wave * 1024 + lane * 16;
  char* lA1 = As + (wave + 4) * 1024 + lane * 16;
  char* lB0 = Bs + wave * 1024 + lane * 16;
  char* lB1 = Bs + (wave + 4) * 1024 + lane * 16;
  const int sw = (lm >> 1) & 3;
  int aoff[4], boff[4];
#pragma unroll
  for (int mi = 0; mi < 4; mi++)
    aoff[mi] = (wr * 64 + mi * 16 + lm) * 64 + (lq ^ sw) * 16;
#pragma unroll
  for (int ni = 0; ni < 4; ni++)
    boff[ni] = (wc * 64 + ni * 16 + lm) * 64 + (lq ^ sw) * 16;

  f32x4 acc[4][4] = {};
  for (int k0 = 0; k0 < K; k0 += 32) {
    __syncthreads();
    glds16(gA0 + k0, lA0);
    glds16(gA1 + k0, lA1);
    glds16(gB0 + k0, lB0);
    glds16(gB1 + k0, lB1);
    __syncthreads();
    short8 af[4], bfr[4];
#pragma unroll
    for (int mi = 0; mi < 4; mi++) af[mi] = *(const short8*)(As + aoff[mi]);
#pragma unroll
    for (int ni = 0; ni < 4; ni++) bfr[ni] = *(const short8*)(Bs + boff[ni]);
#pragma unroll
    for (int mi = 0; mi < 4; mi++)
#pragma unroll
      for (int ni = 0; ni < 4; ni++)
        acc[mi][ni] = __builtin_amdgcn_mfma_f32_16x16x32_bf16(af[mi], bfr[ni], acc[mi][ni], 0, 0, 0);
  }
#pragma unroll
  for (int mi = 0; mi < 4; mi++) {
    const int row0 = m0 + wr * 64 + mi * 16 + lq * 4;
#pragma unroll
    for (int ni = 0; ni < 4; ni++) {
      const int col = n0 + wc * 64 + ni * 16 + lm;
#pragma unroll
      for (int r = 0; r < 4; r++)
        out[(size_t)(row0 + r) * DMODEL + col] = acc[mi][ni][r] + bias[col];
    }
  }
}

// ---------------- tail broadcast: rows >= xlen+128 are identical per batch --------
// out_row = (vsum/2048) @ Wo + bo, computed per block, broadcast to the tail slab.
__global__ __launch_bounds__(256) void tail_kernel(const float* __restrict__ vsum,
                                                   const unsigned short* __restrict__ WoT,
                                                   const float* __restrict__ bo,
                                                   const int* __restrict__ x_len,
                                                   float* __restrict__ out) {
  const int b = blockIdx.y, j = blockIdx.x; // 16 slabs of 128 rows
  const int t0 = min(S_LEN, x_len[b] + 128);
  const int r0 = j * 128, r1 = r0 + 128;
  if (r1 <= t0) return;
  __shared__ float tv[512];
  const float* vs = vsum + b * DMODEL;
  for (int c = threadIdx.x; c < DMODEL; c += 256) {
    const unsigned short* wrow = WoT + (size_t)c * DMODEL;
    float acc = 0.f;
    for (int k = 0; k < DMODEL; k++) acc += vs[k] * bf2f(wrow[k]);
    tv[c] = bo[c] + acc * (1.f / 2048.f);
  }
  __syncthreads();
  const int rs = max(r0, t0);
  const float4 val = ((const float4*)tv)[threadIdx.x & 127];
  for (int r = rs + (threadIdx.x >> 7); r < r1; r += 2)
    ((float4*)(out + (size_t)(b * S_LEN + r) * DMODEL))[threadIdx.x & 127] = val;
}

// ---------------- vsum[b][n] = sum_j Vt[n][b*S+j] (for all-masked fallback) -------
__global__ __launch_bounds__(256) void vsum_kernel(const unsigned short* __restrict__ Vt,
                                                   float* __restrict__ vs) {
  const int wid = blockIdx.x * 4 + (threadIdx.x >> 6);
  const int lane = threadIdx.x & 63;
  const int b = wid >> 9, n = wid & 511;
  const unsigned short* row = Vt + (size_t)n * ROWS + b * S_LEN;
  float s = 0.f;
#pragma unroll
  for (int it = 0; it < 4; it++) {
    uint4 v = *(const uint4*)(row + it * 512 + lane * 8);
    unsigned int w[4] = {v.x, v.y, v.z, v.w};
#pragma unroll
    for (int e = 0; e < 4; e++) {
      s += bf2f((unsigned short)(w[e] & 0xffffu));
      s += bf2f((unsigned short)(w[e] >> 16));
    }
  }
#pragma unroll
  for (int off = 1; off < 64; off <<= 1) s += __shfl_xor(s, off, 64);
  if (lane == 0) vs[(size_t)b * DMODEL + n] = s;
}

// ---------------- banded attention, glds16-staged K/V, no online softmax ----------
// Unpadded LDS tiles with XOR chunk swizzle: phys_chunk = logical ^ f(row), giving
// wave-uniform-base + lane*16 staging (glds16 HW requirement) AND 2-way-max reads.
__global__ __launch_bounds__(256) void attn_kernel(const unsigned short* __restrict__ Q,
                                                   const unsigned short* __restrict__ K,
                                                   const unsigned short* __restrict__ Vt,
                                                   const int* __restrict__ x_len,
                                                   const float* __restrict__ vsum,
                                                   unsigned short* __restrict__ ctx) {
  __shared__ __align__(16) unsigned short Ks[32 * 64];  // 32 keys x 64 dims, swz ^(row&7)
  __shared__ __align__(16) unsigned short Vs[64 * 32];  // 64 dims x 32 keys, swz ^((row>>1)&3)
  __shared__ unsigned short Ps[4][16][40];              // P roundtrip (C->A layout)
  const int tid = threadIdx.x;
  const int wave = tid >> 6, lane = tid & 63;
  const int lm = lane & 15, lq = lane >> 4;
  const int b = blockIdx.z, h = blockIdx.y;
  const int i0 = blockIdx.x * 64;
  const int q0 = i0 + wave * 16;
  const int xlen = x_len[b];

  const size_t qoff = (size_t)(b * S_LEN + q0 + lm) * DMODEL + h * HDIM + lq * 8;
  const short8 aq0 = *(const short8*)(Q + qoff);
  const short8 aq1 = *(const short8*)(Q + qoff + 32);

  // staging maps (per-lane): K row = wave*8 + (lane>>3), phys chunk lane&7
  const int kr = lane >> 3, kp = lane & 7, klc = kp ^ kr;       // logical chunk
  unsigned short* dstK = Ks + wave * 512 + lane * 8;
  const int vr = lane >> 2, vp = lane & 3;
  const int vrow = wave * 16 + vr;                              // dim 0..63
  const int vlc = vp ^ ((vr >> 1) & 3);                         // logical key-chunk
  unsigned short* dstV = Vs + wave * 512 + lane * 8;
  // fragment read swizzles
  const int swk = lm & 7, swv = (lm >> 1) & 3;

  f32x4 oacc[4] = {};
  float lrow[4] = {0.f, 0.f, 0.f, 0.f};

  for (int kt = 0; kt < 10; kt++) {
    const int jt0 = i0 - 128 + kt * 32;
    if (jt0 + 31 < 0 || jt0 >= xlen) continue; // block-uniform: tile fully masked
    __syncthreads();                           // previous tile's LDS reads done
    {
      const int krow_g = jt0 + wave * 8 + kr;
      const int krc = min(max(krow_g, 0), S_LEN - 1);
      glds16(K + (size_t)(b * S_LEN + krc) * DMODEL + h * HDIM + klc * 8, dstK);
      const int jv = jt0 + vlc * 8;
      const int jvc = min(max(jv, 0), S_LEN - 8);
      glds16(Vt + (size_t)(h * HDIM + vrow) * ROWS + b * S_LEN + jvc, dstV);
    }
    __syncthreads();
    // wave skip: tile outside this wave's band window
    if (jt0 + 31 < q0 - 128 || jt0 > q0 + 143) continue;

    f32x4 sv[2];
#pragma unroll
    for (int sub = 0; sub < 2; sub++) {
      const int krow = (sub * 16 + lm) * 64;
      const short8 bk0 = *(const short8*)&Ks[krow + ((lq ^ swk) * 8)];
      const short8 bk1 = *(const short8*)&Ks[krow + (((lq + 4) ^ swk) * 8)];
      f32x4 s = {};
      s = __builtin_amdgcn_mfma_f32_16x16x32_bf16(aq0, bk0, s, 0, 0, 0);
      s = __builtin_amdgcn_mfma_f32_16x16x32_bf16(aq1, bk1, s, 0, 0, 0);
      sv[sub] = s;
    }
    // mask + exp (no max shift; logits bounded, fp32 exp cannot overflow)
    float p[2][4];
#pragma unroll
    for (int sub = 0; sub < 2; sub++) {
      const int j = jt0 + sub * 16 + lm;
      const bool jv = (j >= 0) && (j < xlen);
#pragma unroll
      for (int r = 0; r < 4; r++) {
        const int i = q0 + lq * 4 + r;
        const bool ok = jv && (j - i <= 128) && (i - j <= 128);
        const float pv = ok ? __expf(sv[sub][r] * 0.125f) : 0.f;
        p[sub][r] = pv;
        lrow[r] += pv;
      }
    }
#pragma unroll
    for (int r = 0; r < 4; r++) {
      Ps[wave][lq * 4 + r][lm] = f2bf(p[0][r]);
      Ps[wave][lq * 4 + r][16 + lm] = f2bf(p[1][r]);
    }
    // within-wave DS write->read is in program order: no barrier needed
    const short8 pf = *(const short8*)&Ps[wave][lm][lq * 8];
#pragma unroll
    for (int dt = 0; dt < 4; dt++) {
      const short8 bv = *(const short8*)&Vs[(dt * 16 + lm) * 32 + ((lq ^ swv) * 8)];
      oacc[dt] = __builtin_amdgcn_mfma_f32_16x16x32_bf16(pf, bv, oacc[dt], 0, 0, 0);
    }
  }
  // single cross-lane reduce of the row sums
#pragma unroll
  for (int r = 0; r < 4; r++)
#pragma unroll
    for (int off = 1; off < 16; off <<= 1) lrow[r] += __shfl_xor(lrow[r], off, 64);

#pragma unroll
  for (int r = 0; r < 4; r++) {
    const int i = q0 + lq * 4 + r;
    const size_t obase = (size_t)(b * S_LEN + i) * DMODEL + h * HDIM;
    if (lrow[r] > 0.f) {
      const float inv = 1.f / lrow[r];
#pragma unroll
      for (int dt = 0; dt < 4; dt++)
        ctx[obase + dt * 16 + lm] = f2bf(oacc[dt][r] * inv);
    } else {
      // all keys masked -> reference softmax exactly uniform over ALL 2048 keys
#pragma unroll
      for (int dt = 0; dt < 4; dt++)
        ctx[obase + dt * 16 + lm] =
            f2bf(vsum[(size_t)b * DMODEL + h * HDIM + dt * 16 + lm] * (1.f / 2048.f));
    }
  }
}

extern "C" void kernel_launch(void* const* d_in, const int* in_sizes, int n_in,
                              void* d_out, int out_size, void* d_ws, size_t ws_size,
                              hipStream_t stream) {
  (void)in_sizes; (void)n_in; (void)out_size; (void)ws_size;
  const float* x  = (const float*)d_in[0];
  const float* Wq = (const float*)d_in[1];
  const float* bq = (const float*)d_in[2];
  const float* Wk = (const float*)d_in[3];
  const float* bk = (const float*)d_in[4];
  const float* Wv = (const float*)d_in[5];
  const float* bv = (const float*)d_in[6];
  const float* Wo = (const float*)d_in[7];
  const float* bo = (const float*)d_in[8];
  const int* x_len = (const int*)d_in[9];

  char* ws = (char*)d_ws;
  const size_t MB = 1024 * 1024;
  unsigned short* xb   = (unsigned short*)(ws + 0 * MB);   // [8192][512]
  unsigned short* Qb   = (unsigned short*)(ws + 8 * MB);   // [8192][512]
  unsigned short* Kb   = (unsigned short*)(ws + 16 * MB);  // [8192][512]
  unsigned short* Vt   = (unsigned short*)(ws + 24 * MB);  // [512][8192]
  unsigned short* Cx   = (unsigned short*)(ws + 32 * MB);  // [8192][512]
  unsigned short* WqkT = (unsigned short*)(ws + 40 * MB);  // [1024][512]: Wq^T | Wk^T
  unsigned short* WvT  = (unsigned short*)(ws + 41 * MB);  // [512][512]
  unsigned short* WoT  = (unsigned short*)(ws + 41 * MB + 512 * 1024);
  float* vsum          = (float*)(ws + 42 * MB);           // [4][512]

  prep_kernel<<<3072, 256, 0, stream>>>(x, Wq, Wk, Wv, Wo, xb, WqkT, WvT, WoT);
  gemm_qkv_kernel<<<768, 256, 0, stream>>>(xb, WqkT, WvT, bq, bk, bv, x_len, Qb, Kb, Vt);
  vsum_kernel<<<512, 256, 0, stream>>>(Vt, vsum);
  attn_kernel<<<dim3(32, 8, 4), 256, 0, stream>>>(Qb, Kb, Vt, x_len, vsum, Cx);
  gemm_out_kernel<<<dim3(4, 64), 256, 0, stream>>>(Cx, WoT, bo, x_len, (float*)d_out);
  tail_kernel<<<dim3(16, 4), 256, 0, stream>>>(vsum, WoT, bo, x_len, (float*)d_out);
}

// Round 7
// 148.947 us; speedup vs baseline: 1.1299x; 1.1299x over previous
//
#include <hip/hip_runtime.h>

#define S_LEN 2048
#define BATCH 4
#define DMODEL 512
#define NHEAD 8
#define HDIM 64
#define ROWS (BATCH * S_LEN) /* 8192 */

using short8 = __attribute__((ext_vector_type(8))) short;
using f32x4  = __attribute__((ext_vector_type(4))) float;

__device__ __forceinline__ unsigned short f2bf(float f) {
  unsigned int u = __builtin_bit_cast(unsigned int, f);
  u += 0x7fffu + ((u >> 16) & 1u);
  return (unsigned short)(u >> 16);
}
__device__ __forceinline__ float bf2f(unsigned short h) {
  unsigned int u = ((unsigned int)h) << 16;
  return __builtin_bit_cast(float, u);
}
__device__ __forceinline__ void glds16(const void* g, void* l) {
  __builtin_amdgcn_global_load_lds((const __attribute__((address_space(1))) unsigned*)g,
                                   (__attribute__((address_space(3))) unsigned*)l, 16, 0, 0);
}

// ---------------- prep: fp32->bf16 cvt (blocks 0..2047) + 4 weight transposes ------
__global__ __launch_bounds__(256) void prep_kernel(const float* __restrict__ x,
                                                   const float* __restrict__ Wq,
                                                   const float* __restrict__ Wk,
                                                   const float* __restrict__ Wv,
                                                   const float* __restrict__ Wo,
                                                   unsigned short* __restrict__ xb,
                                                   unsigned short* __restrict__ WqkT,
                                                   unsigned short* __restrict__ WvT,
                                                   unsigned short* __restrict__ WoT) {
  __shared__ float t[32][33];
  const int blk = blockIdx.x, tid = threadIdx.x;
  if (blk < 2048) {
    const int base = (blk * 256 + tid) * 8;
    float4 f0 = *(const float4*)(x + base);
    float4 f1 = *(const float4*)(x + base + 4);
    uint4 o;
    o.x = (unsigned)f2bf(f0.x) | ((unsigned)f2bf(f0.y) << 16);
    o.y = (unsigned)f2bf(f0.z) | ((unsigned)f2bf(f0.w) << 16);
    o.z = (unsigned)f2bf(f1.x) | ((unsigned)f2bf(f1.y) << 16);
    o.w = (unsigned)f2bf(f1.z) | ((unsigned)f2bf(f1.w) << 16);
    *(uint4*)(xb + base) = o;
    return;
  }
  const int tb = blk - 2048;   // 0..1023
  const int which = tb >> 8;   // matrix id
  const int tile = tb & 255;   // 16x16 grid of 32x32 tiles
  const float* W = which == 0 ? Wq : which == 1 ? Wk : which == 2 ? Wv : Wo;
  unsigned short* WT = which == 0 ? WqkT : which == 1 ? (WqkT + 512 * 512)
                      : which == 2 ? WvT : WoT;
  const int tx = tid & 31, ty = tid >> 5; // 32 x 8
  const int x0 = (tile & 15) * 32, y0 = (tile >> 4) * 32;
#pragma unroll
  for (int r = 0; r < 4; r++)
    t[ty + 8 * r][tx] = W[(size_t)(y0 + ty + 8 * r) * DMODEL + x0 + tx];
  __syncthreads();
#pragma unroll
  for (int r = 0; r < 4; r++)
    WT[(size_t)(x0 + ty + 8 * r) * DMODEL + y0 + tx] = f2bf(t[tx][ty + 8 * r]);
}

// ---------------- fused QKV GEMM: 1D grid, 768 blocks -----------------------------
__global__ __launch_bounds__(256, 2) void gemm_qkv_kernel(const unsigned short* __restrict__ xb,
                                                          const unsigned short* __restrict__ WqkT,
                                                          const unsigned short* __restrict__ WvT,
                                                          const float* __restrict__ bq,
                                                          const float* __restrict__ bk,
                                                          const float* __restrict__ bv,
                                                          const int* __restrict__ x_len,
                                                          unsigned short* __restrict__ Qb,
                                                          unsigned short* __restrict__ Kb,
                                                          unsigned short* __restrict__ Vt) {
  constexpr int K = DMODEL;
  __shared__ __align__(16) char smem[16384];
  char* As = smem;
  char* Bs = smem + 8192;
  const int bid = blockIdx.x;
  const bool vmode = bid < 256;
  const unsigned short *A, *Bt;
  int m0, n0;
  if (vmode) {
    m0 = (bid & 3) * 128;   // feature
    n0 = (bid >> 2) * 128;  // row
    A = WvT; Bt = xb;
  } else {
    const int q = bid - 256;
    m0 = (q >> 3) * 128;    // row
    n0 = (q & 7) * 128;     // col (0-511 Q, 512-1023 K)
    A = xb; Bt = WqkT;
    const int xl = x_len[m0 >> 11];
    const int s0 = m0 & 2047;
    if (n0 >= DMODEL) { if (s0 >= xl) return; }        // K rows >= xlen unobserved
    else if (s0 >= xl + 128) return;                   // Q rows >= xlen+128 unobserved
  }
  const int tid = threadIdx.x;
  const int wave = tid >> 6, lane = tid & 63;
  const int wr = wave >> 1, wc = wave & 1;
  const int lm = lane & 15, lq = lane >> 4;
  const int lr = lane >> 2;
  const int lc = (lane & 3) ^ ((lane >> 3) & 3);
  const unsigned short* gA0 = A + (size_t)(m0 + wave * 16 + lr) * K + lc * 8;
  const unsigned short* gA1 = A + (size_t)(m0 + (wave + 4) * 16 + lr) * K + lc * 8;
  const unsigned short* gB0 = Bt + (size_t)(n0 + wave * 16 + lr) * K + lc * 8;
  const unsigned short* gB1 = Bt + (size_t)(n0 + (wave + 4) * 16 + lr) * K + lc * 8;
  char* lA0 = As + wave * 1024 + lane * 16;
  char* lA1 = As + (wave + 4) * 1024 + lane * 16;
  char* lB0 = Bs + wave * 1024 + lane * 16;
  char* lB1 = Bs + (wave + 4) * 1024 + lane * 16;
  const int sw = (lm >> 1) & 3;
  int aoff[4], boff[4];
#pragma unroll
  for (int mi = 0; mi < 4; mi++)
    aoff[mi] = (wr * 64 + mi * 16 + lm) * 64 + (lq ^ sw) * 16;
#pragma unroll
  for (int ni = 0; ni < 4; ni++)
    boff[ni] = (wc * 64 + ni * 16 + lm) * 64 + (lq ^ sw) * 16;

  f32x4 acc[4][4] = {};
  for (int k0 = 0; k0 < K; k0 += 32) {
    __syncthreads();
    glds16(gA0 + k0, lA0);
    glds16(gA1 + k0, lA1);
    glds16(gB0 + k0, lB0);
    glds16(gB1 + k0, lB1);
    __syncthreads();
    short8 af[4], bfr[4];
#pragma unroll
    for (int mi = 0; mi < 4; mi++) af[mi] = *(const short8*)(As + aoff[mi]);
#pragma unroll
    for (int ni = 0; ni < 4; ni++) bfr[ni] = *(const short8*)(Bs + boff[ni]);
#pragma unroll
    for (int mi = 0; mi < 4; mi++)
#pragma unroll
      for (int ni = 0; ni < 4; ni++)
        acc[mi][ni] = __builtin_amdgcn_mfma_f32_16x16x32_bf16(af[mi], bfr[ni], acc[mi][ni], 0, 0, 0);
  }
#pragma unroll
  for (int mi = 0; mi < 4; mi++) {
    const int row0 = m0 + wr * 64 + mi * 16 + lq * 4;
#pragma unroll
    for (int ni = 0; ni < 4; ni++) {
      const int col = n0 + wc * 64 + ni * 16 + lm;
#pragma unroll
      for (int r = 0; r < 4; r++) {
        const int row = row0 + r;
        const float v = acc[mi][ni][r];
        if (vmode) {
          Vt[(size_t)row * ROWS + col] = f2bf(v + bv[row]);
        } else if (col < DMODEL) {
          Qb[(size_t)row * DMODEL + col] = f2bf(v + bq[col]);
        } else {
          Kb[(size_t)row * DMODEL + (col - DMODEL)] = f2bf(v + bk[col - DMODEL]);
        }
      }
    }
  }
}

// ---------------- vsum[b][n] = sum_j Vt[n][b*S+j] (for all-masked fallback) -------
__global__ __launch_bounds__(256) void vsum_kernel(const unsigned short* __restrict__ Vt,
                                                   float* __restrict__ vs) {
  const int wid = blockIdx.x * 4 + (threadIdx.x >> 6);
  const int lane = threadIdx.x & 63;
  const int b = wid >> 9, n = wid & 511;
  const unsigned short* row = Vt + (size_t)n * ROWS + b * S_LEN;
  float s = 0.f;
#pragma unroll
  for (int it = 0; it < 4; it++) {
    uint4 v = *(const uint4*)(row + it * 512 + lane * 8);
    unsigned int w[4] = {v.x, v.y, v.z, v.w};
#pragma unroll
    for (int e = 0; e < 4; e++) {
      s += bf2f((unsigned short)(w[e] & 0xffffu));
      s += bf2f((unsigned short)(w[e] >> 16));
    }
  }
#pragma unroll
  for (int off = 1; off < 64; off <<= 1) s += __shfl_xor(s, off, 64);
  if (lane == 0) vs[(size_t)b * DMODEL + n] = s;
}

// ---------------- tailrow[b][c] = bo[c] + (vsum[b]/2048) . WoT[c] -----------------
// One wave per column: 64 lanes x 8 bf16 coalesced, one butterfly reduce. 8 cols/wave.
__global__ __launch_bounds__(256) void tailrow_kernel(const float* __restrict__ vsum,
                                                      const unsigned short* __restrict__ WoT,
                                                      const float* __restrict__ bo,
                                                      float* __restrict__ trow) {
  const int b = blockIdx.y;
  const int wave = threadIdx.x >> 6, lane = threadIdx.x & 63;
  const float* vs = vsum + b * DMODEL + lane * 8;
  float vreg[8];
  *(float4*)vreg = *(const float4*)vs;
  *(float4*)(vreg + 4) = *(const float4*)(vs + 4);
#pragma unroll
  for (int ci = 0; ci < 8; ci++) {
    const int c = blockIdx.x * 32 + wave * 8 + ci;
    const uint4 wv = *(const uint4*)(WoT + (size_t)c * DMODEL + lane * 8);
    const unsigned int w[4] = {wv.x, wv.y, wv.z, wv.w};
    float acc = 0.f;
#pragma unroll
    for (int e = 0; e < 4; e++) {
      acc += vreg[2 * e] * bf2f((unsigned short)(w[e] & 0xffffu));
      acc += vreg[2 * e + 1] * bf2f((unsigned short)(w[e] >> 16));
    }
#pragma unroll
    for (int off = 1; off < 64; off <<= 1) acc += __shfl_xor(acc, off, 64);
    if (lane == 0) trow[b * DMODEL + c] = bo[c] + acc * (1.f / 2048.f);
  }
}

// ---------------- banded attention (R5 staging), no online softmax ----------------
__global__ __launch_bounds__(256) void attn_kernel(const unsigned short* __restrict__ Q,
                                                   const unsigned short* __restrict__ K,
                                                   const unsigned short* __restrict__ Vt,
                                                   const int* __restrict__ x_len,
                                                   const float* __restrict__ vsum,
                                                   unsigned short* __restrict__ ctx) {
  __shared__ unsigned short Ks[32][72];     // 32 keys x 64 dims (+pad)
  __shared__ unsigned short Vs[64][40];     // 64 dims x 32 keys (+pad)
  __shared__ unsigned short Ps[4][16][40];  // per-wave P roundtrip (C->A layout)
  const int tid = threadIdx.x;
  const int wave = tid >> 6, lane = tid & 63;
  const int lm = lane & 15, lq = lane >> 4;
  const int b = blockIdx.z, h = blockIdx.y;
  const int i0 = blockIdx.x * 64;
  const int q0 = i0 + wave * 16;
  const int xlen = x_len[b];
  const int t0 = min(S_LEN, xlen + 128);
  if ((i0 & ~127) >= t0) return; // whole 128-slab is tail: gemm_out broadcasts it

  const size_t qoff = (size_t)(b * S_LEN + q0 + lm) * DMODEL + h * HDIM + lq * 8;
  const short8 aq0 = *(const short8*)(Q + qoff);
  const short8 aq1 = *(const short8*)(Q + qoff + 32);

  const int krow = tid >> 3, kchk = (tid & 7) * 8; // K staging: 32 rows x 8 chunks
  const int vdim = tid >> 2, vchk = (tid & 3) * 8; // V staging: 64 dims x 4 chunks

  f32x4 oacc[4] = {};
  float lrow[4] = {0.f, 0.f, 0.f, 0.f};

  for (int kt = 0; kt < 10; kt++) {
    const int jt0 = i0 - 128 + kt * 32;
    if (jt0 + 31 < 0 || jt0 >= xlen) continue; // block-uniform: tile fully masked
    __syncthreads();                           // previous tile's LDS reads done
    {
      const int jr = jt0 + krow;
      const int jrc = min(max(jr, 0), S_LEN - 1);
      *(uint4*)&Ks[krow][kchk] =
          *(const uint4*)(K + (size_t)(b * S_LEN + jrc) * DMODEL + h * HDIM + kchk);
      const int jv = jt0 + vchk;
      const int jvc = min(max(jv, 0), S_LEN - 8);
      *(uint4*)&Vs[vdim][vchk] =
          *(const uint4*)(Vt + (size_t)(h * HDIM + vdim) * ROWS + b * S_LEN + jvc);
    }
    __syncthreads();
    // wave skip: tile outside this wave's band window
    if (jt0 + 31 < q0 - 128 || jt0 > q0 + 143) continue;

    f32x4 sv[2];
#pragma unroll
    for (int sub = 0; sub < 2; sub++) {
      const short8 bk0 = *(const short8*)&Ks[sub * 16 + lm][lq * 8];
      const short8 bk1 = *(const short8*)&Ks[sub * 16 + lm][32 + lq * 8];
      f32x4 s = {};
      s = __builtin_amdgcn_mfma_f32_16x16x32_bf16(aq0, bk0, s, 0, 0, 0);
      s = __builtin_amdgcn_mfma_f32_16x16x32_bf16(aq1, bk1, s, 0, 0, 0);
      sv[sub] = s;
    }
    // mask + exp (no max shift; logits bounded, fp32 exp cannot overflow)
    float p[2][4];
#pragma unroll
    for (int sub = 0; sub < 2; sub++) {
      const int j = jt0 + sub * 16 + lm;
      const bool jv = (j >= 0) && (j < xlen);
#pragma unroll
      for (int r = 0; r < 4; r++) {
        const int i = q0 + lq * 4 + r;
        const bool ok = jv && (j - i <= 128) && (i - j <= 128);
        const float pv = ok ? __expf(sv[sub][r] * 0.125f) : 0.f;
        p[sub][r] = pv;
        lrow[r] += pv;
      }
    }
#pragma unroll
    for (int r = 0; r < 4; r++) {
      Ps[wave][lq * 4 + r][lm] = f2bf(p[0][r]);
      Ps[wave][lq * 4 + r][16 + lm] = f2bf(p[1][r]);
    }
    // within-wave DS write->read is in program order: no barrier needed
    const short8 pf = *(const short8*)&Ps[wave][lm][lq * 8];
#pragma unroll
    for (int dt = 0; dt < 4; dt++) {
      const short8 bv = *(const short8*)&Vs[dt * 16 + lm][lq * 8];
      oacc[dt] = __builtin_amdgcn_mfma_f32_16x16x32_bf16(pf, bv, oacc[dt], 0, 0, 0);
    }
  }
  // single cross-lane reduce of the row sums
#pragma unroll
  for (int r = 0; r < 4; r++)
#pragma unroll
    for (int off = 1; off < 16; off <<= 1) lrow[r] += __shfl_xor(lrow[r], off, 64);

#pragma unroll
  for (int r = 0; r < 4; r++) {
    const int i = q0 + lq * 4 + r;
    const size_t obase = (size_t)(b * S_LEN + i) * DMODEL + h * HDIM;
    if (lrow[r] > 0.f) {
      const float inv = 1.f / lrow[r];
#pragma unroll
      for (int dt = 0; dt < 4; dt++)
        ctx[obase + dt * 16 + lm] = f2bf(oacc[dt][r] * inv);
    } else {
      // all keys masked -> reference softmax exactly uniform over ALL 2048 keys
#pragma unroll
      for (int dt = 0; dt < 4; dt++)
        ctx[obase + dt * 16 + lm] =
            f2bf(vsum[(size_t)b * DMODEL + h * HDIM + dt * 16 + lm] * (1.f / 2048.f));
    }
  }
}

// ---------------- output projection GEMM; tail blocks broadcast trow --------------
__global__ __launch_bounds__(256, 2) void gemm_out_kernel(const unsigned short* __restrict__ A,
                                                          const unsigned short* __restrict__ Bt,
                                                          const float* __restrict__ bias,
                                                          const int* __restrict__ x_len,
                                                          const float* __restrict__ trow,
                                                          float* __restrict__ out) {
  constexpr int K = DMODEL;
  __shared__ __align__(16) char smem[16384];
  char* As = smem;
  char* Bs = smem + 8192;
  const int tid = threadIdx.x;
  const int m0 = blockIdx.y * 128, n0 = blockIdx.x * 128;
  {
    const int xl = x_len[m0 >> 11];
    if ((m0 & 2047) >= min(S_LEN, xl + 128)) {
      // whole slab is tail: every row equals trow (batch-uniform); coalesced bcast
      const float4 val = *(const float4*)(trow + (m0 >> 11) * DMODEL + n0 + (tid & 31) * 4);
      float* obase = out + (size_t)m0 * DMODEL + n0 + (tid & 31) * 4;
#pragma unroll
      for (int r = tid >> 5; r < 128; r += 8)
        *(float4*)(obase + (size_t)r * DMODEL) = val;
      return;
    }
  }
  const int wave = tid >> 6, lane = tid & 63;
  const int wr = wave >> 1, wc = wave & 1;
  const int lm = lane & 15, lq = lane >> 4;
  const int lr = lane >> 2;
  const int lc = (lane & 3) ^ ((lane >> 3) & 3);
  const unsigned short* gA0 = A + (size_t)(m0 + wave * 16 + lr) * K + lc * 8;
  const unsigned short* gA1 = A + (size_t)(m0 + (wave + 4) * 16 + lr) * K + lc * 8;
  const unsigned short* gB0 = Bt + (size_t)(n0 + wave * 16 + lr) * K + lc * 8;
  const unsigned short* gB1 = Bt + (size_t)(n0 + (wave + 4) * 16 + lr) * K + lc * 8;
  char* lA0 = As + wave * 1024 + lane * 16;
  char* lA1 = As + (wave + 4) * 1024 + lane * 16;
  char* lB0 = Bs + wave * 1024 + lane * 16;
  char* lB1 = Bs + (wave + 4) * 1024 + lane * 16;
  const int sw = (lm >> 1) & 3;
  int aoff[4], boff[4];
#pragma unroll
  for (int mi = 0; mi < 4; mi++)
    aoff[mi] = (wr * 64 + mi * 16 + lm) * 64 + (lq ^ sw) * 16;
#pragma unroll
  for (int ni = 0; ni < 4; ni++)
    boff[ni] = (wc * 64 + ni * 16 + lm) * 64 + (lq ^ sw) * 16;

  f32x4 acc[4][4] = {};
  for (int k0 = 0; k0 < K; k0 += 32) {
    __syncthreads();
    glds16(gA0 + k0, lA0);
    glds16(gA1 + k0, lA1);
    glds16(gB0 + k0, lB0);
    glds16(gB1 + k0, lB1);
    __syncthreads();
    short8 af[4], bfr[4];
#pragma unroll
    for (int mi = 0; mi < 4; mi++) af[mi] = *(const short8*)(As + aoff[mi]);
#pragma unroll
    for (int ni = 0; ni < 4; ni++) bfr[ni] = *(const short8*)(Bs + boff[ni]);
#pragma unroll
    for (int mi = 0; mi < 4; mi++)
#pragma unroll
      for (int ni = 0; ni < 4; ni++)
        acc[mi][ni] = __builtin_amdgcn_mfma_f32_16x16x32_bf16(af[mi], bfr[ni], acc[mi][ni], 0, 0, 0);
  }
#pragma unroll
  for (int mi = 0; mi < 4; mi++) {
    const int row0 = m0 + wr * 64 + mi * 16 + lq * 4;
#pragma unroll
    for (int ni = 0; ni < 4; ni++) {
      const int col = n0 + wc * 64 + ni * 16 + lm;
#pragma unroll
      for (int r = 0; r < 4; r++)
        out[(size_t)(row0 + r) * DMODEL + col] = acc[mi][ni][r] + bias[col];
    }
  }
}

extern "C" void kernel_launch(void* const* d_in, const int* in_sizes, int n_in,
                              void* d_out, int out_size, void* d_ws, size_t ws_size,
                              hipStream_t stream) {
  (void)in_sizes; (void)n_in; (void)out_size; (void)ws_size;
  const float* x  = (const float*)d_in[0];
  const float* Wq = (const float*)d_in[1];
  const float* bq = (const float*)d_in[2];
  const float* Wk = (const float*)d_in[3];
  const float* bk = (const float*)d_in[4];
  const float* Wv = (const float*)d_in[5];
  const float* bv = (const float*)d_in[6];
  const float* Wo = (const float*)d_in[7];
  const float* bo = (const float*)d_in[8];
  const int* x_len = (const int*)d_in[9];

  char* ws = (char*)d_ws;
  const size_t MB = 1024 * 1024;
  unsigned short* xb   = (unsigned short*)(ws + 0 * MB);   // [8192][512]
  unsigned short* Qb   = (unsigned short*)(ws + 8 * MB);   // [8192][512]
  unsigned short* Kb   = (unsigned short*)(ws + 16 * MB);  // [8192][512]
  unsigned short* Vt   = (unsigned short*)(ws + 24 * MB);  // [512][8192]
  unsigned short* Cx   = (unsigned short*)(ws + 32 * MB);  // [8192][512]
  unsigned short* WqkT = (unsigned short*)(ws + 40 * MB);  // [1024][512]: Wq^T | Wk^T
  unsigned short* WvT  = (unsigned short*)(ws + 41 * MB);  // [512][512]
  unsigned short* WoT  = (unsigned short*)(ws + 41 * MB + 512 * 1024);
  float* vsum          = (float*)(ws + 42 * MB);           // [4][512]
  float* trow          = (float*)(ws + 42 * MB + 8192);    // [4][512]

  prep_kernel<<<3072, 256, 0, stream>>>(x, Wq, Wk, Wv, Wo, xb, WqkT, WvT, WoT);
  gemm_qkv_kernel<<<768, 256, 0, stream>>>(xb, WqkT, WvT, bq, bk, bv, x_len, Qb, Kb, Vt);
  vsum_kernel<<<512, 256, 0, stream>>>(Vt, vsum);
  tailrow_kernel<<<dim3(16, 4), 256, 0, stream>>>(vsum, WoT, bo, trow);
  attn_kernel<<<dim3(32, 8, 4), 256, 0, stream>>>(Qb, Kb, Vt, x_len, vsum, Cx);
  gemm_out_kernel<<<dim3(4, 64), 256, 0, stream>>>(Cx, WoT, bo, x_len, trow, (float*)d_out);
}